// Round 1
// baseline (9848.485 us; speedup 1.0000x reference)
//
#include <hip/hip_runtime.h>
#include <hip/hip_bf16.h>

// SigLIP attention, fp32 baseline (round 1: correctness + counters).
// B=16 L=1025 C=1024 H=16 hd=64. ws layout: Q,K,V [B][H][L][64], AO [B][L][C].

#define Bv 16
#define Lv 1025
#define Cv 1024
#define Hv 16
#define HDv 64
#define Mv (Bv * Lv)          // 16400 rows
#define SZv ((size_t)Bv * Hv * Lv * HDv)  // 16,793,600 elements per tensor

// ---------------- QKV GEMM: qkv[m][n] = sum_k x[m][k] * qkv_w[n][k] ----------
// 64x64 output tile per block, 4x4 per thread, BK=32. Epilogue scatters to
// Q/K/V in [B][H][L][hd] layout.
__global__ __launch_bounds__(256) void qkv_gemm(const float* __restrict__ x,
                                                const float* __restrict__ w,
                                                float* __restrict__ Q,
                                                float* __restrict__ K,
                                                float* __restrict__ V) {
    __shared__ float As[64][33];   // +1 pad
    __shared__ float Bs[32][65];   // transposed store, stride 65 -> conflict-free
    const int tid = threadIdx.x;
    const int tx = tid & 15, ty = tid >> 4;
    const int m0 = blockIdx.y * 64;
    const int n0 = blockIdx.x * 64;
    float acc[4][4] = {};
    for (int k0 = 0; k0 < 1024; k0 += 32) {
#pragma unroll
        for (int i = 0; i < 8; i++) {
            int e = tid + i * 256;
            int r = e >> 5, c = e & 31;
            int m = m0 + r;
            As[r][c] = (m < Mv) ? x[(size_t)m * 1024 + k0 + c] : 0.f;
        }
#pragma unroll
        for (int i = 0; i < 8; i++) {
            int e = tid + i * 256;
            int r = e >> 5, c = e & 31;  // r: n offset, c: k offset
            Bs[c][r] = w[(size_t)(n0 + r) * 1024 + k0 + c];
        }
        __syncthreads();
#pragma unroll
        for (int kk = 0; kk < 32; kk++) {
            float a[4], b[4];
#pragma unroll
            for (int i = 0; i < 4; i++) a[i] = As[ty * 4 + i][kk];
#pragma unroll
            for (int j = 0; j < 4; j++) b[j] = Bs[kk][tx * 4 + j];
#pragma unroll
            for (int i = 0; i < 4; i++)
#pragma unroll
                for (int j = 0; j < 4; j++) acc[i][j] += a[i] * b[j];
        }
        __syncthreads();
    }
#pragma unroll
    for (int i = 0; i < 4; i++) {
        int m = m0 + ty * 4 + i;
        if (m >= Mv) continue;
        int b = m / Lv, l = m % Lv;
#pragma unroll
        for (int j = 0; j < 4; j++) {
            int n = n0 + tx * 4 + j;
            int which = n >> 10;
            int h = (n & 1023) >> 6;
            int d = n & 63;
            size_t idx = ((size_t)(b * Hv + h) * Lv + l) * HDv + d;
            float vv = acc[i][j];
            if (which == 0) Q[idx] = vv;
            else if (which == 1) K[idx] = vv;
            else V[idx] = vv;
        }
    }
}

// ---------------- RoPE in-place on Q and K patch rows (l = 1..1024) ----------
// One wave handles one 64-wide row: all loads complete before the store
// (in-order wave execution), so the d <-> d+-32 exchange is race-free.
__global__ __launch_bounds__(256) void rope_kernel(float* __restrict__ Q,
                                                   float* __restrict__ K,
                                                   const float* __restrict__ sinp,
                                                   const float* __restrict__ cosp) {
    const int ROWS = Bv * Hv * 1024;  // per tensor
    int row = blockIdx.x * 4 + (threadIdx.x >> 6);
    int d = threadIdx.x & 63;
    float* arr = (row < ROWS) ? Q : K;
    int r = (row < ROWS) ? row : row - ROWS;
    int bh = r >> 10;
    int lm1 = r & 1023;
    size_t base = ((size_t)bh * Lv + (lm1 + 1)) * HDv;
    float v = arr[base + d];
    float p = (d < 32) ? -arr[base + d + 32] : arr[base + d - 32];
    float s = sinp[lm1 * 64 + d];
    float c = cosp[lm1 * 64 + d];
    arr[base + d] = v * c + p * s;
}

// ---------------- Attention: block = (b, h, 32-query tile) ------------------
// Unnormalized-exp accumulation (logits are O(1): q,k ~ N(0,0.4), scale=1/8,
// so exp never overflows; softmax shift-invariance => exact same result).
__global__ __launch_bounds__(256) void attn_kernel(const float* __restrict__ Q,
                                                   const float* __restrict__ K,
                                                   const float* __restrict__ V,
                                                   float* __restrict__ AO) {
    __shared__ float Qs[32][65];
    __shared__ float Ks[64][65];
    __shared__ float Vs[64][65];
    __shared__ float Ps[32][65];
    const int tid = threadIdx.x;
    const int bid = blockIdx.x;
    const int qt = bid % 33;       // 33 q-tiles of 32 cover L=1025
    const int bh = bid / 33;
    const int q0 = qt * 32;
    const size_t base = (size_t)bh * Lv * HDv;

#pragma unroll
    for (int i = 0; i < 8; i++) {  // Q tile 32x64
        int e = tid + i * 256;
        int r = e >> 6, c = e & 63;
        int l = q0 + r;
        Qs[r][c] = (l < Lv) ? Q[base + (size_t)l * HDv + c] : 0.f;
    }

    const int qq = tid >> 3;   // 0..31 query within tile
    const int sub = tid & 7;   // 0..7  key-group / dim-group
    float acc[8] = {};
    float sume = 0.f;
    const float scale = 0.125f;  // hd^-0.5 = 1/8

    for (int k0 = 0; k0 < Lv; k0 += 64) {
        __syncthreads();  // protect Ks/Vs/Ps from previous iteration readers
#pragma unroll
        for (int i = 0; i < 16; i++) {  // K tile 64x64
            int e = tid + i * 256;
            int r = e >> 6, c = e & 63;
            int l = k0 + r;
            Ks[r][c] = (l < Lv) ? K[base + (size_t)l * HDv + c] : 0.f;
        }
#pragma unroll
        for (int i = 0; i < 16; i++) {  // V tile 64x64
            int e = tid + i * 256;
            int r = e >> 6, c = e & 63;
            int l = k0 + r;
            Vs[r][c] = (l < Lv) ? V[base + (size_t)l * HDv + c] : 0.f;
        }
        __syncthreads();
        // scores: thread -> (q = qq, keys sub*8 .. sub*8+7)
        float s[8] = {};
#pragma unroll
        for (int d = 0; d < 64; d++) {
            float qv = Qs[qq][d];
#pragma unroll
            for (int j = 0; j < 8; j++) s[j] += qv * Ks[sub * 8 + j][d];
        }
#pragma unroll
        for (int j = 0; j < 8; j++) {
            bool valid = (k0 + sub * 8 + j) < Lv;
            float p = valid ? __expf(s[j] * scale) : 0.f;
            sume += p;
            Ps[qq][sub * 8 + j] = p;
        }
        __syncthreads();
        // PV: thread -> (q = qq, dims sub*8 .. sub*8+7)
#pragma unroll
        for (int k = 0; k < 64; k++) {
            float p = Ps[qq][k];
#pragma unroll
            for (int j = 0; j < 8; j++) acc[j] += p * Vs[k][sub * 8 + j];
        }
    }
    // reduce sum-of-exp across the 8 lanes sharing this q (contiguous lanes)
#pragma unroll
    for (int off = 1; off < 8; off <<= 1) sume += __shfl_xor(sume, off);

    int l = q0 + qq;
    if (l < Lv) {
        int b = bh >> 4, h = bh & 15;
        float inv = 1.f / sume;
        size_t ob = ((size_t)b * Lv + l) * Cv + h * 64 + sub * 8;
#pragma unroll
        for (int j = 0; j < 8; j++) AO[ob + j] = acc[j] * inv;
    }
}

// ---------------- Proj GEMM: out[m][n] = sum_k AO[m][k]*proj_w[n][k] + b[n] --
__global__ __launch_bounds__(256) void proj_gemm(const float* __restrict__ A,
                                                 const float* __restrict__ w,
                                                 const float* __restrict__ bias,
                                                 float* __restrict__ out) {
    __shared__ float As[64][33];
    __shared__ float Bs[32][65];
    const int tid = threadIdx.x;
    const int tx = tid & 15, ty = tid >> 4;
    const int m0 = blockIdx.y * 64;
    const int n0 = blockIdx.x * 64;
    float acc[4][4] = {};
    for (int k0 = 0; k0 < 1024; k0 += 32) {
#pragma unroll
        for (int i = 0; i < 8; i++) {
            int e = tid + i * 256;
            int r = e >> 5, c = e & 31;
            int m = m0 + r;
            As[r][c] = (m < Mv) ? A[(size_t)m * 1024 + k0 + c] : 0.f;
        }
#pragma unroll
        for (int i = 0; i < 8; i++) {
            int e = tid + i * 256;
            int r = e >> 5, c = e & 31;
            Bs[c][r] = w[(size_t)(n0 + r) * 1024 + k0 + c];
        }
        __syncthreads();
#pragma unroll
        for (int kk = 0; kk < 32; kk++) {
            float a[4], b[4];
#pragma unroll
            for (int i = 0; i < 4; i++) a[i] = As[ty * 4 + i][kk];
#pragma unroll
            for (int j = 0; j < 4; j++) b[j] = Bs[kk][tx * 4 + j];
#pragma unroll
            for (int i = 0; i < 4; i++)
#pragma unroll
                for (int j = 0; j < 4; j++) acc[i][j] += a[i] * b[j];
        }
        __syncthreads();
    }
#pragma unroll
    for (int i = 0; i < 4; i++) {
        int m = m0 + ty * 4 + i;
        if (m >= Mv) continue;
#pragma unroll
        for (int j = 0; j < 4; j++) {
            int n = n0 + tx * 4 + j;
            out[(size_t)m * 1024 + n] = acc[i][j] + bias[n];
        }
    }
}

extern "C" void kernel_launch(void* const* d_in, const int* in_sizes, int n_in,
                              void* d_out, int out_size, void* d_ws, size_t ws_size,
                              hipStream_t stream) {
    (void)in_sizes; (void)n_in; (void)out_size; (void)ws_size;
    const float* x      = (const float*)d_in[0];
    const float* sinp   = (const float*)d_in[1];
    const float* cosp   = (const float*)d_in[2];
    const float* qkv_w  = (const float*)d_in[3];
    const float* proj_w = (const float*)d_in[4];
    const float* proj_b = (const float*)d_in[5];
    float* out = (float*)d_out;

    float* Q  = (float*)d_ws;          // [B][H][L][64]
    float* K  = Q + SZv;
    float* V  = K + SZv;
    float* AO = V + SZv;               // [B][L][C]

    dim3 blk(256);
    qkv_gemm<<<dim3(48, 257), blk, 0, stream>>>(x, qkv_w, Q, K, V);
    rope_kernel<<<dim3((2 * Bv * Hv * 1024) / 4), blk, 0, stream>>>(Q, K, sinp, cosp);
    attn_kernel<<<dim3(Bv * Hv * 33), blk, 0, stream>>>(Q, K, V, AO);
    proj_gemm<<<dim3(16, 257), blk, 0, stream>>>(AO, proj_w, proj_b, out);
}

// Round 2
// 1040.250 us; speedup vs baseline: 9.4674x; 9.4674x over previous
//
#include <hip/hip_runtime.h>

typedef unsigned short ushort_t;
typedef unsigned int uint_t;
typedef __attribute__((ext_vector_type(8))) short short8;
typedef __attribute__((ext_vector_type(4))) float f32x4;

#define Bv 16
#define Lv 1025
#define LpD 1088          // 17*64 padded sequence
#define Cv 1024
#define Hv 16
#define BHv 256
#define Mv 16400          // valid rows
#define Mp 16512          // 129*128 padded rows

#define MFMA(a, b, c) __builtin_amdgcn_mfma_f32_16x16x32_bf16(a, b, c, 0, 0, 0)

__device__ __forceinline__ ushort_t f2b(float x) {
    uint_t u = __float_as_uint(x);
    u = (u + 0x7FFFu + ((u >> 16) & 1u)) >> 16;   // RNE
    return (ushort_t)u;
}
__device__ __forceinline__ float b2f(ushort_t v) {
    return __uint_as_float(((uint_t)v) << 16);
}

// ---------------- fp32 -> bf16 convert (pads tail with zeros) ---------------
__global__ __launch_bounds__(256) void conv_bf16(const float* __restrict__ s,
                                                 ushort_t* __restrict__ d,
                                                 int n_valid, int n_total) {
    int i = (blockIdx.x * 256 + threadIdx.x) * 4;
    if (i >= n_total) return;
    float4 v = make_float4(0.f, 0.f, 0.f, 0.f);
    if (i < n_valid) v = *(const float4*)(s + i);   // n_valid multiple of 4
    ushort4 o;
    o.x = f2b(v.x); o.y = f2b(v.y); o.z = f2b(v.z); o.w = f2b(v.w);
    *(ushort4*)(d + i) = o;
}

// ---------------- QKV GEMM: C[m][n] = sum_k A[m][k] W[n][k], scatter --------
__global__ __launch_bounds__(256, 2) void gemm_qkv(const ushort_t* __restrict__ A,
                                                   const ushort_t* __restrict__ W,
                                                   ushort_t* __restrict__ Q,
                                                   ushort_t* __restrict__ K,
                                                   ushort_t* __restrict__ V) {
    __shared__ ushort_t As[128][72];   // 144B rows: b128 frag reads ~2-4-way max
    __shared__ ushort_t Bs[128][72];
    const int t = threadIdx.x;
    const int w = t >> 6, l = t & 63;
    const int m0 = blockIdx.y * 128, n0 = blockIdx.x * 128;
    const int wm = (w >> 1) * 64, wn = (w & 1) * 64;
    f32x4 acc[4][4] = {};
    uint4 pa[4], pb[4];
#pragma unroll
    for (int i = 0; i < 4; i++) {
        int c = t + 256 * i; int row = c >> 3, cir = c & 7;
        pa[i] = *(const uint4*)(A + (size_t)(m0 + row) * 1024 + cir * 8);
        pb[i] = *(const uint4*)(W + (size_t)(n0 + row) * 1024 + cir * 8);
    }
    for (int k0 = 0; k0 < 1024; k0 += 64) {
        __syncthreads();
#pragma unroll
        for (int i = 0; i < 4; i++) {
            int c = t + 256 * i; int row = c >> 3, cir = c & 7;
            *(uint4*)&As[row][cir * 8] = pa[i];
            *(uint4*)&Bs[row][cir * 8] = pb[i];
        }
        __syncthreads();
        if (k0 + 64 < 1024) {
#pragma unroll
            for (int i = 0; i < 4; i++) {
                int c = t + 256 * i; int row = c >> 3, cir = c & 7;
                pa[i] = *(const uint4*)(A + (size_t)(m0 + row) * 1024 + k0 + 64 + cir * 8);
                pb[i] = *(const uint4*)(W + (size_t)(n0 + row) * 1024 + k0 + 64 + cir * 8);
            }
        }
#pragma unroll
        for (int kb = 0; kb < 2; kb++) {
            short8 af[4], bf[4];
#pragma unroll
            for (int mb = 0; mb < 4; mb++)
                af[mb] = *(const short8*)&As[wm + mb * 16 + (l & 15)][kb * 32 + (l >> 4) * 8];
#pragma unroll
            for (int nb = 0; nb < 4; nb++)
                bf[nb] = *(const short8*)&Bs[wn + nb * 16 + (l & 15)][kb * 32 + (l >> 4) * 8];
#pragma unroll
            for (int mb = 0; mb < 4; mb++)
#pragma unroll
                for (int nb = 0; nb < 4; nb++)
                    acc[mb][nb] = MFMA(af[mb], bf[nb], acc[mb][nb]);
        }
    }
    // epilogue: C-layout row=(l>>4)*4+r, col=l&15; scatter to [BH][Lp][64]
#pragma unroll
    for (int mb = 0; mb < 4; mb++) {
#pragma unroll
        for (int r = 0; r < 4; r++) {
            int m = m0 + wm + mb * 16 + (l >> 4) * 4 + r;
            if (m >= Mv) continue;
            int b = m / 1025, lseq = m - b * 1025;
#pragma unroll
            for (int nb = 0; nb < 4; nb++) {
                int n = n0 + wn + nb * 16 + (l & 15);
                int which = n >> 10, h = (n >> 6) & 15, dd = n & 63;
                ushort_t* dst = (which == 0) ? Q : ((which == 1) ? K : V);
                dst[((size_t)(b * Hv + h) * LpD + lseq) * 64 + dd] = f2b(acc[mb][nb][r]);
            }
        }
    }
}

// ---------------- RoPE in-place on bf16 Q,K (rows l=1..1024) ----------------
__global__ __launch_bounds__(256) void rope_bf16(ushort_t* __restrict__ Qb,
                                                 ushort_t* __restrict__ Kb,
                                                 const float* __restrict__ sinp,
                                                 const float* __restrict__ cosp) {
    const int ROWS = BHv * 1024;
    int row = blockIdx.x * 4 + (threadIdx.x >> 6);
    int d = threadIdx.x & 63;
    ushort_t* arr = (row < ROWS) ? Qb : Kb;
    int r = (row < ROWS) ? row : row - ROWS;
    int bh = r >> 10, lm1 = r & 1023;
    size_t a = ((size_t)bh * LpD + lm1 + 1) * 64 + d;
    float f = b2f(arr[a]);
    float p = __shfl_xor(f, 32);
    p = (d < 32) ? -p : p;
    arr[a] = f2b(f * cosp[lm1 * 64 + d] + p * sinp[lm1 * 64 + d]);
}

// ---------------- V transpose: [BH][Lp][64] -> [BH][64][Lp] -----------------
__global__ __launch_bounds__(256) void transpose_v(const ushort_t* __restrict__ Vb,
                                                   ushort_t* __restrict__ Vt) {
    __shared__ ushort_t Ts[64][72];
    const int t = threadIdx.x;
    const int l0 = blockIdx.x * 64, bh = blockIdx.y;
#pragma unroll
    for (int i = 0; i < 2; i++) {
        int c = t + 256 * i; int row = c >> 3, cir = c & 7;
        *(uint4*)&Ts[row][cir * 8] =
            *(const uint4*)(Vb + ((size_t)bh * LpD + l0 + row) * 64 + cir * 8);
    }
    __syncthreads();
#pragma unroll
    for (int i = 0; i < 2; i++) {
        int c = t + 256 * i; int d = c >> 3, lg = c & 7;
        short8 v;
#pragma unroll
        for (int j = 0; j < 8; j++) v[j] = (short)Ts[lg * 8 + j][d];
        *(short8*)(Vt + ((size_t)bh * 64 + d) * LpD + l0 + lg * 8) = v;
    }
}

// ---------------- Attention: block = (q-tile 64, bh). Unnormalized exp. -----
__global__ __launch_bounds__(256, 4) void attn_mfma(const ushort_t* __restrict__ Qb,
                                                    const ushort_t* __restrict__ Kb,
                                                    const ushort_t* __restrict__ Vt,
                                                    ushort_t* __restrict__ AO) {
    __shared__ ushort_t Qs[64][72], Ks[64][72], Vs[64][72], Ps[64][72];
    const int t = threadIdx.x, w = t >> 6, l = t & 63;
    const int qt = blockIdx.x, bh = blockIdx.y;
    const int q0 = qt * 64;
    const size_t kbase = (size_t)bh * LpD * 64;
    const size_t vbase = (size_t)bh * 64 * LpD;
#pragma unroll
    for (int i = 0; i < 2; i++) {
        int c = t + 256 * i; int row = c >> 3, cir = c & 7;
        *(uint4*)&Qs[row][cir * 8] =
            *(const uint4*)(Qb + kbase + (size_t)(q0 + row) * 64 + cir * 8);
    }
    __syncthreads();
    // Q A-frags live in registers for the whole K loop
    short8 aq0 = *(const short8*)&Qs[w * 16 + (l & 15)][(l >> 4) * 8];
    short8 aq1 = *(const short8*)&Qs[w * 16 + (l & 15)][32 + (l >> 4) * 8];
    f32x4 o[4] = {};
    float sume[4] = {0.f, 0.f, 0.f, 0.f};
    const float CE = 0.18033688011112042f;  // log2(e)/8: exp(s/8) = exp2(s*CE)

    for (int kt = 0; kt < 17; kt++) {
        __syncthreads();
#pragma unroll
        for (int i = 0; i < 2; i++) {
            int c = t + 256 * i; int row = c >> 3, cir = c & 7;
            *(uint4*)&Ks[row][cir * 8] =
                *(const uint4*)(Kb + kbase + (size_t)(kt * 64 + row) * 64 + cir * 8);
            *(uint4*)&Vs[row][cir * 8] =
                *(const uint4*)(Vt + vbase + (size_t)row * LpD + kt * 64 + cir * 8);
        }
        __syncthreads();
#pragma unroll
        for (int cb = 0; cb < 4; cb++) {
            short8 bk0 = *(const short8*)&Ks[cb * 16 + (l & 15)][(l >> 4) * 8];
            short8 bk1 = *(const short8*)&Ks[cb * 16 + (l & 15)][32 + (l >> 4) * 8];
            f32x4 s = {};
            s = MFMA(aq0, bk0, s);
            s = MFMA(aq1, bk1, s);
            int key = kt * 64 + cb * 16 + (l & 15);
            bool valid = key < Lv;   // padded keys must contribute exactly 0
#pragma unroll
            for (int r = 0; r < 4; r++) {
                float p = valid ? exp2f(s[r] * CE) : 0.f;
                sume[r] += p;
                Ps[w * 16 + (l >> 4) * 4 + r][cb * 16 + (l & 15)] = f2b(p);
            }
        }
        // own-wave rows only -> no barrier; compiler inserts lgkmcnt waits
        short8 ap0 = *(const short8*)&Ps[w * 16 + (l & 15)][(l >> 4) * 8];
        short8 ap1 = *(const short8*)&Ps[w * 16 + (l & 15)][32 + (l >> 4) * 8];
#pragma unroll
        for (int cb = 0; cb < 4; cb++) {
            short8 bv0 = *(const short8*)&Vs[cb * 16 + (l & 15)][(l >> 4) * 8];
            short8 bv1 = *(const short8*)&Vs[cb * 16 + (l & 15)][32 + (l >> 4) * 8];
            o[cb] = MFMA(ap0, bv0, o[cb]);
            o[cb] = MFMA(ap1, bv1, o[cb]);
        }
    }
#pragma unroll
    for (int r = 0; r < 4; r++) {
        float s_ = sume[r];
        s_ += __shfl_xor(s_, 1); s_ += __shfl_xor(s_, 2);
        s_ += __shfl_xor(s_, 4); s_ += __shfl_xor(s_, 8);
        sume[r] = 1.f / s_;      // row sums; row map matches C-layout rows
    }
    const int b = bh >> 4, h = bh & 15;
#pragma unroll
    for (int r = 0; r < 4; r++) {
        int lq = q0 + w * 16 + (l >> 4) * 4 + r;
        if (lq >= Lv) continue;
        size_t ob = ((size_t)(b * 1025 + lq)) * 1024 + h * 64;
#pragma unroll
        for (int cb = 0; cb < 4; cb++)
            AO[ob + cb * 16 + (l & 15)] = f2b(o[cb][r] * sume[r]);
    }
}

// ---------------- Proj GEMM + bias, fp32 out --------------------------------
__global__ __launch_bounds__(256, 2) void gemm_proj(const ushort_t* __restrict__ A,
                                                    const ushort_t* __restrict__ W,
                                                    const float* __restrict__ bias,
                                                    float* __restrict__ out) {
    __shared__ ushort_t As[128][72];
    __shared__ ushort_t Bs[128][72];
    const int t = threadIdx.x;
    const int w = t >> 6, l = t & 63;
    const int m0 = blockIdx.y * 128, n0 = blockIdx.x * 128;
    const int wm = (w >> 1) * 64, wn = (w & 1) * 64;
    f32x4 acc[4][4] = {};
    uint4 pa[4], pb[4];
#pragma unroll
    for (int i = 0; i < 4; i++) {
        int c = t + 256 * i; int row = c >> 3, cir = c & 7;
        pa[i] = *(const uint4*)(A + (size_t)(m0 + row) * 1024 + cir * 8);
        pb[i] = *(const uint4*)(W + (size_t)(n0 + row) * 1024 + cir * 8);
    }
    for (int k0 = 0; k0 < 1024; k0 += 64) {
        __syncthreads();
#pragma unroll
        for (int i = 0; i < 4; i++) {
            int c = t + 256 * i; int row = c >> 3, cir = c & 7;
            *(uint4*)&As[row][cir * 8] = pa[i];
            *(uint4*)&Bs[row][cir * 8] = pb[i];
        }
        __syncthreads();
        if (k0 + 64 < 1024) {
#pragma unroll
            for (int i = 0; i < 4; i++) {
                int c = t + 256 * i; int row = c >> 3, cir = c & 7;
                pa[i] = *(const uint4*)(A + (size_t)(m0 + row) * 1024 + k0 + 64 + cir * 8);
                pb[i] = *(const uint4*)(W + (size_t)(n0 + row) * 1024 + k0 + 64 + cir * 8);
            }
        }
#pragma unroll
        for (int kb = 0; kb < 2; kb++) {
            short8 af[4], bf[4];
#pragma unroll
            for (int mb = 0; mb < 4; mb++)
                af[mb] = *(const short8*)&As[wm + mb * 16 + (l & 15)][kb * 32 + (l >> 4) * 8];
#pragma unroll
            for (int nb = 0; nb < 4; nb++)
                bf[nb] = *(const short8*)&Bs[wn + nb * 16 + (l & 15)][kb * 32 + (l >> 4) * 8];
#pragma unroll
            for (int mb = 0; mb < 4; mb++)
#pragma unroll
                for (int nb = 0; nb < 4; nb++)
                    acc[mb][nb] = MFMA(af[mb], bf[nb], acc[mb][nb]);
        }
    }
#pragma unroll
    for (int mb = 0; mb < 4; mb++) {
#pragma unroll
        for (int r = 0; r < 4; r++) {
            int m = m0 + wm + mb * 16 + (l >> 4) * 4 + r;
            if (m >= Mv) continue;
#pragma unroll
            for (int nb = 0; nb < 4; nb++) {
                int n = n0 + wn + nb * 16 + (l & 15);
                out[(size_t)m * 1024 + n] = acc[mb][nb][r] + bias[n];
            }
        }
    }
}

extern "C" void kernel_launch(void* const* d_in, const int* in_sizes, int n_in,
                              void* d_out, int out_size, void* d_ws, size_t ws_size,
                              hipStream_t stream) {
    (void)in_sizes; (void)n_in; (void)out_size; (void)ws_size;
    const float* x      = (const float*)d_in[0];
    const float* sinp   = (const float*)d_in[1];
    const float* cosp   = (const float*)d_in[2];
    const float* qkv_w  = (const float*)d_in[3];
    const float* proj_w = (const float*)d_in[4];
    const float* proj_b = (const float*)d_in[5];
    float* out = (float*)d_out;

    const size_t SZH = (size_t)BHv * LpD * 64;     // per Q/K/V tensor (bf16 elems)
    ushort_t* xb  = (ushort_t*)d_ws;               // [Mp][1024]
    ushort_t* qwb = xb + (size_t)Mp * 1024;        // [3072][1024]
    ushort_t* pwb = qwb + (size_t)3072 * 1024;     // [1024][1024]
    ushort_t* Qb  = pwb + (size_t)1024 * 1024;     // [BH][Lp][64]
    ushort_t* Kb  = Qb + SZH;
    ushort_t* Vb  = Kb + SZH;
    ushort_t* Vt  = Vb + SZH;                      // [BH][64][Lp]
    ushort_t* AO  = Vt + SZH;                      // [Mp][1024]

    dim3 blk(256);
    conv_bf16<<<dim3(Mp * 1024 / 1024), blk, 0, stream>>>(x, xb, Mv * 1024, Mp * 1024);
    conv_bf16<<<dim3(3072 * 1024 / 1024), blk, 0, stream>>>(qkv_w, qwb, 3072 * 1024, 3072 * 1024);
    conv_bf16<<<dim3(1024 * 1024 / 1024), blk, 0, stream>>>(proj_w, pwb, 1024 * 1024, 1024 * 1024);
    gemm_qkv<<<dim3(24, 129), blk, 0, stream>>>(xb, qwb, Qb, Kb, Vb);
    rope_bf16<<<dim3(2 * BHv * 1024 / 4), blk, 0, stream>>>(Qb, Kb, sinp, cosp);
    transpose_v<<<dim3(17, BHv), blk, 0, stream>>>(Vb, Vt);
    attn_mfma<<<dim3(17, BHv), blk, 0, stream>>>(Qb, Kb, Vt, AO);
    gemm_proj<<<dim3(8, 129), blk, 0, stream>>>(AO, pwb, proj_b, out);
}